// Round 8
// baseline (873.286 us; speedup 1.0000x reference)
//
#include <hip/hip_runtime.h>

#define N_NODES 100000
#define N_EDGES 1600000
#define D_IN    256
#define D_HID   64
#define D_OUT   40
#define PROP_N  16

typedef short short8 __attribute__((ext_vector_type(8)));   // 8 bf16 (4 VGPRs)
typedef float f32x4  __attribute__((ext_vector_type(4)));   // MFMA accumulator
typedef unsigned int   u32x4 __attribute__((ext_vector_type(4)));   // nt-load ok
typedef unsigned short u16x4 __attribute__((ext_vector_type(4)));   // nt-load ok

// ---- fp8 (OCP e4m3) helpers: HW convert, RNE, saturating ------------------
__device__ __forceinline__ unsigned char f32_to_fp8(float f) {
    int p = __builtin_amdgcn_cvt_pk_fp8_f32(f, f, 0, false);
    return (unsigned char)(p & 0xff);
}
// ---- bf16 helpers (RNE) ---------------------------------------------------
__device__ __forceinline__ unsigned short f32_to_bf16(float f) {
    unsigned int u = __float_as_uint(f);
    unsigned int r = (u + 0x7fffu + ((u >> 16) & 1u)) >> 16;
    return (unsigned short)r;
}
__device__ __forceinline__ unsigned int f32x2_to_bf16x2(float lo, float hi) {
    return (unsigned int)f32_to_bf16(lo) | ((unsigned int)f32_to_bf16(hi) << 16);
}
__device__ __forceinline__ float bf16_f(unsigned short u) {
    return __uint_as_float(((unsigned)u) << 16);
}
// decode packed edge: bits[31:15]=col, bits[14:0]=bf16(val) without sign
__device__ __forceinline__ float edge_val(unsigned p) {
    return __uint_as_float((p & 0x7fffu) << 16);
}
// 4-feature fp8 FMA: b holds 4 fp8 bytes
__device__ __forceinline__ void fma4(float4& a, float v, unsigned b) {
    a.x = fmaf(v, __builtin_amdgcn_cvt_f32_fp8((int)b, 0), a.x);
    a.y = fmaf(v, __builtin_amdgcn_cvt_f32_fp8((int)b, 1), a.y);
    a.z = fmaf(v, __builtin_amdgcn_cvt_f32_fp8((int)b, 2), a.z);
    a.w = fmaf(v, __builtin_amdgcn_cvt_f32_fp8((int)b, 3), a.w);
}

// ---------------------------------------------------------------------------
// Kernel 1: CSR row_ptr from sorted edge_row via binary search.
// ---------------------------------------------------------------------------
__global__ __launch_bounds__(256) void build_rowptr(const int* __restrict__ erow,
                                                    int* __restrict__ rp) {
    int r = blockIdx.x * blockDim.x + threadIdx.x;
    if (r > N_NODES) return;
    int lo = 0, hi = N_EDGES;
    while (lo < hi) {
        int mid = (lo + hi) >> 1;
        if (erow[mid] < r) lo = mid + 1; else hi = mid;
    }
    rp[r] = lo;
}

// ---------------------------------------------------------------------------
// Kernel 1b: pack (col, val) into ONE dword.
//   bits[31:15] = col (100000 < 2^17), bits[14:0] = bf16(val) sans sign.
// ---------------------------------------------------------------------------
__global__ __launch_bounds__(256) void pack_edges4(const int* __restrict__ ecol,
                                                   const float* __restrict__ evalv,
                                                   unsigned* __restrict__ ep4) {
    int i = blockIdx.x * blockDim.x + threadIdx.x;
    if (i >= N_EDGES) return;
    unsigned bf = f32_to_bf16(evalv[i]);
    ep4[i] = ((unsigned)ecol[i] << 15) | (bf & 0x7fffu);
}

// ---------------------------------------------------------------------------
// Kernel 1c: W1 [256][64] fp32 -> W1T [64][256] bf16 (for MFMA B-fragments).
// ---------------------------------------------------------------------------
__global__ __launch_bounds__(256) void prep_w1t(const float* __restrict__ W1,
                                                unsigned short* __restrict__ W1T) {
    int i = blockIdx.x * 256 + threadIdx.x;           // 16384 elements
    if (i >= D_IN * D_HID) return;
    int k = i >> 6, n = i & 63;
    W1T[n * 256 + k] = f32_to_bf16(W1[i]);
}

// ---------------------------------------------------------------------------
// Kernel 2 (MFMA): h = x @ W1 + b1. EXACT R4 core — FROZEN. Four structures
// tried (sync loads / reg-preload / K-split / async global_load_lds): all
// land 60-70 us; this one is the 59.5 us floor (per-CU line-service cap).
// Epilogue writes bf16 Y, bf16 src, fp8 Y8.
// ---------------------------------------------------------------------------
__global__ __launch_bounds__(64) void mlp1(const float* __restrict__ x,
                                           const unsigned short* __restrict__ W1T,
                                           const float* __restrict__ b1,
                                           const float* __restrict__ diag,
                                           unsigned short* __restrict__ Yb,
                                           unsigned char* __restrict__ Y08,
                                           unsigned short* __restrict__ srcb) {
    const int lane  = threadIdx.x;
    const int l15   = lane & 15;
    const int quad  = lane >> 4;
    const int mbase = blockIdx.x * 16;      // 6250 * 16 == 100000 exactly

    f32x4 acc[4] = {};
    const float* xrow = x + (size_t)(mbase + l15) * D_IN + quad * 8;

    #pragma unroll
    for (int ks = 0; ks < 8; ++ks) {
        float4 f0 = *(const float4*)(xrow + ks * 32);
        float4 f1 = *(const float4*)(xrow + ks * 32 + 4);
        union { short8 v; unsigned int u[4]; } a;
        a.u[0] = f32x2_to_bf16x2(f0.x, f0.y);
        a.u[1] = f32x2_to_bf16x2(f0.z, f0.w);
        a.u[2] = f32x2_to_bf16x2(f1.x, f1.y);
        a.u[3] = f32x2_to_bf16x2(f1.z, f1.w);

        #pragma unroll
        for (int ct = 0; ct < 4; ++ct) {
            short8 b = *(const short8*)(W1T + (ct * 16 + l15) * 256 + ks * 32 + quad * 8);
            acc[ct] = __builtin_amdgcn_mfma_f32_16x16x32_bf16(a.v, b, acc[ct], 0, 0, 0);
        }
    }

    float bias[4];
    #pragma unroll
    for (int ct = 0; ct < 4; ++ct) bias[ct] = b1[ct * 16 + l15];

    #pragma unroll
    for (int reg = 0; reg < 4; ++reg) {
        const int mr = mbase + quad * 4 + reg;
        const float dg = diag[mr];
        #pragma unroll
        for (int ct = 0; ct < 4; ++ct) {
            const int col = ct * 16 + l15;
            const float h = acc[ct][reg] + bias[ct];
            const size_t idx = (size_t)mr * 64 + col;
            Yb[idx]   = f32_to_bf16(h);
            srcb[idx] = f32_to_bf16(0.5f * dg * h);
            Y08[idx]  = f32_to_fp8(h);
        }
    }
}

// ---------------------------------------------------------------------------
// Kernel 3: one propagation step. R4 structure (42 us/step known-best).
// CHANGE (R6 theory, compile-fixed): the three pure STREAM loads (ep4,
// Yb-self, srcb) use __builtin_nontemporal_load via ext_vector_type
// typedefs (HIP_vector_type classes are rejected by the builtin). Theory:
// these streams (~4MB/XCD/step, never L2-re-read) evict Y8's ~5MB gather
// set from the 4MiB per-XCD L2; removing the pollution reprices gathers
// from ~13.9 toward ~6.6 cyc/line at ZERO added traffic.
// Gather loads + both stores stay cached (Yo8 is next step's gather target).
// ---------------------------------------------------------------------------
__global__ __launch_bounds__(256) void prop_step(const unsigned short* __restrict__ Yb,
                                                 const unsigned char* __restrict__ Y8,
                                                 const unsigned short* __restrict__ srcb,
                                                 unsigned short* __restrict__ Ybo,
                                                 unsigned char* __restrict__ Yo8,
                                                 const int* __restrict__ rp,
                                                 const unsigned* __restrict__ ep4) {
    const int wid  = blockIdx.x * 4 + (threadIdx.x >> 6);   // 25000 waves
    const int lane = threadIdx.x & 63;
    const int g    = lane >> 4;         // row group 0..3
    const int fl   = lane & 15;         // feature-quad index
    const int row  = wid * 4 + g;       // exact: 100000 = 4 * 25000

    const int e0 = rp[row];
    const int e1 = rp[row + 1];

    const size_t fb = (size_t)row * 64 + fl * 4;
    const u16x4 ys4 = __builtin_nontemporal_load((const u16x4*)(Yb + fb));
    const u16x4 sv4 = __builtin_nontemporal_load((const u16x4*)(srcb + fb));
    const float4 yself = make_float4(bf16_f(ys4.x), bf16_f(ys4.y),
                                     bf16_f(ys4.z), bf16_f(ys4.w));
    const float4 sv    = make_float4(bf16_f(sv4.x), bf16_f(sv4.y),
                                     bf16_f(sv4.z), bf16_f(sv4.w));
    const unsigned char* Y8f = Y8 + fl * 4;

    float4 acc0 = make_float4(0.f, 0.f, 0.f, 0.f);
    float4 acc1 = acc0, acc2 = acc0, acc3 = acc0;

    int e = e0;
    // scalar head until e is 4-aligned (16B-aligned vector loads)
    int ea = (e0 + 3) & ~3;
    if (ea > e1) ea = e1;
    for (; e < ea; ++e) {
        unsigned p = __builtin_nontemporal_load(ep4 + e);
        unsigned b = *(const unsigned*)(Y8f + ((size_t)(p >> 15) << 6));
        fma4(acc0, edge_val(p), b);
    }
    for (; e + 8 <= e1; e += 8) {
        u32x4 pa = __builtin_nontemporal_load((const u32x4*)(ep4 + e));
        u32x4 pb = __builtin_nontemporal_load((const u32x4*)(ep4 + e + 4));
        unsigned b0 = *(const unsigned*)(Y8f + ((size_t)(pa.x >> 15) << 6));
        unsigned b1 = *(const unsigned*)(Y8f + ((size_t)(pa.y >> 15) << 6));
        unsigned b2 = *(const unsigned*)(Y8f + ((size_t)(pa.z >> 15) << 6));
        unsigned b3 = *(const unsigned*)(Y8f + ((size_t)(pa.w >> 15) << 6));
        unsigned b4 = *(const unsigned*)(Y8f + ((size_t)(pb.x >> 15) << 6));
        unsigned b5 = *(const unsigned*)(Y8f + ((size_t)(pb.y >> 15) << 6));
        unsigned b6 = *(const unsigned*)(Y8f + ((size_t)(pb.z >> 15) << 6));
        unsigned b7 = *(const unsigned*)(Y8f + ((size_t)(pb.w >> 15) << 6));
        fma4(acc0, edge_val(pa.x), b0);
        fma4(acc1, edge_val(pa.y), b1);
        fma4(acc2, edge_val(pa.z), b2);
        fma4(acc3, edge_val(pa.w), b3);
        fma4(acc0, edge_val(pb.x), b4);
        fma4(acc1, edge_val(pb.y), b5);
        fma4(acc2, edge_val(pb.z), b6);
        fma4(acc3, edge_val(pb.w), b7);
    }
    if (e + 4 <= e1) {
        u32x4 pa = __builtin_nontemporal_load((const u32x4*)(ep4 + e));
        unsigned b0 = *(const unsigned*)(Y8f + ((size_t)(pa.x >> 15) << 6));
        unsigned b1 = *(const unsigned*)(Y8f + ((size_t)(pa.y >> 15) << 6));
        unsigned b2 = *(const unsigned*)(Y8f + ((size_t)(pa.z >> 15) << 6));
        unsigned b3 = *(const unsigned*)(Y8f + ((size_t)(pa.w >> 15) << 6));
        fma4(acc0, edge_val(pa.x), b0);
        fma4(acc1, edge_val(pa.y), b1);
        fma4(acc2, edge_val(pa.z), b2);
        fma4(acc3, edge_val(pa.w), b3);
        e += 4;
    }
    for (; e < e1; ++e) {
        unsigned p = __builtin_nontemporal_load(ep4 + e);
        unsigned b = *(const unsigned*)(Y8f + ((size_t)(p >> 15) << 6));
        fma4(acc0, edge_val(p), b);
    }

    float4 accs;
    accs.x = (acc0.x + acc1.x) + (acc2.x + acc3.x);
    accs.y = (acc0.y + acc1.y) + (acc2.y + acc3.y);
    accs.z = (acc0.z + acc1.z) + (acc2.z + acc3.z);
    accs.w = (acc0.w + acc1.w) + (acc2.w + acc3.w);

    float4 o;
    o.x = fmaf(0.5f, yself.x, fmaf(0.5f, accs.x, sv.x));
    o.y = fmaf(0.5f, yself.y, fmaf(0.5f, accs.y, sv.y));
    o.z = fmaf(0.5f, yself.z, fmaf(0.5f, accs.z, sv.z));
    o.w = fmaf(0.5f, yself.w, fmaf(0.5f, accs.w, sv.w));

    ushort4 ob;
    ob.x = f32_to_bf16(o.x); ob.y = f32_to_bf16(o.y);
    ob.z = f32_to_bf16(o.z); ob.w = f32_to_bf16(o.w);
    *(ushort4*)(Ybo + fb) = ob;
    int pk = __builtin_amdgcn_cvt_pk_fp8_f32(o.x, o.y, 0, false);   // bytes 0,1
    pk     = __builtin_amdgcn_cvt_pk_fp8_f32(o.z, o.w, pk, true);   // bytes 2,3
    *(unsigned*)(Yo8 + fb) = (unsigned)pk;
}

// ---------------------------------------------------------------------------
// Kernel 4: out = relu(Y) @ W2 + b2. Y bf16 (uint4 = 8 features/load).
// ---------------------------------------------------------------------------
__global__ __launch_bounds__(256) void mlp2(const unsigned short* __restrict__ Yb,
                                            const float* __restrict__ W2,
                                            const float* __restrict__ b2,
                                            float* __restrict__ out) {
    __shared__ float W2s[D_HID * D_OUT];
    __shared__ float b2s[D_OUT];
    int tid = threadIdx.x;
    for (int i = tid; i < D_HID * D_OUT; i += 256) W2s[i] = W2[i];
    if (tid < D_OUT) b2s[tid] = b2[tid];
    __syncthreads();

    int n = blockIdx.x * 256 + tid;
    if (n >= N_NODES) return;

    float acc[D_OUT];
    #pragma unroll
    for (int o = 0; o < D_OUT; ++o) acc[o] = b2s[o];

    const uint4* Y4 = (const uint4*)(Yb + (size_t)n * 64);
    #pragma unroll
    for (int k8 = 0; k8 < 8; ++k8) {
        uint4 y = Y4[k8];
        unsigned w[4] = {y.x, y.y, y.z, y.w};
        #pragma unroll
        for (int d = 0; d < 4; ++d) {
            float lo = fmaxf(__uint_as_float((w[d] & 0xffffu) << 16), 0.0f);
            float hi = fmaxf(__uint_as_float(w[d] & 0xffff0000u), 0.0f);
            int klo = k8 * 8 + 2 * d, khi = klo + 1;
            #pragma unroll
            for (int o = 0; o < D_OUT; ++o)
                acc[o] = fmaf(lo, W2s[klo * D_OUT + o], acc[o]);
            #pragma unroll
            for (int o = 0; o < D_OUT; ++o)
                acc[o] = fmaf(hi, W2s[khi * D_OUT + o], acc[o]);
        }
    }

    float4* o4 = (float4*)(out + (size_t)n * D_OUT);
    #pragma unroll
    for (int q = 0; q < 10; ++q)
        o4[q] = make_float4(acc[4 * q], acc[4 * q + 1], acc[4 * q + 2], acc[4 * q + 3]);
}

// ---------------------------------------------------------------------------
extern "C" void kernel_launch(void* const* d_in, const int* in_sizes, int n_in,
                              void* d_out, int out_size, void* d_ws, size_t ws_size,
                              hipStream_t stream) {
    const float* x     = (const float*)d_in[0];
    const int*   erow  = (const int*)  d_in[1];
    const int*   ecol  = (const int*)  d_in[2];
    const float* evalv = (const float*)d_in[3];
    const float* diag  = (const float*)d_in[4];
    const float* W1    = (const float*)d_in[5];
    const float* b1    = (const float*)d_in[6];
    const float* W2    = (const float*)d_in[7];
    const float* b2    = (const float*)d_in[8];
    float* out = (float*)d_out;

    // workspace: Yb0|Yb1|srcb (bf16) | Y08|Y18 (fp8) | ep4 | rp | W1T
    const size_t NV = (size_t)N_NODES * D_HID;
    unsigned short* Yb0  = (unsigned short*)d_ws;
    unsigned short* Yb1  = Yb0 + NV;
    unsigned short* srcb = Yb1 + NV;
    unsigned char*  Y08  = (unsigned char*)(srcb + NV);
    unsigned char*  Y18  = Y08 + NV;
    unsigned*       ep4  = (unsigned*)(Y18 + NV);
    int*            rp   = (int*)(ep4 + N_EDGES);
    unsigned short* W1T  = (unsigned short*)
        (((unsigned long long)(rp + N_NODES + 1) + 15ull) & ~15ull);

    build_rowptr<<<(N_NODES + 1 + 255) / 256, 256, 0, stream>>>(erow, rp);
    pack_edges4<<<(N_EDGES + 255) / 256, 256, 0, stream>>>(ecol, evalv, ep4);
    prep_w1t<<<(D_IN * D_HID + 255) / 256, 256, 0, stream>>>(W1, W1T);
    mlp1<<<N_NODES / 16, 64, 0, stream>>>(x, W1T, b1, diag, Yb0, Y08, srcb);

    unsigned short* Yb[2] = {Yb0, Yb1};
    unsigned char*  Y8[2] = {Y08, Y18};
    for (int i = 0; i < PROP_N; ++i) {
        prop_step<<<N_NODES / 16, 256, 0, stream>>>(
            Yb[i & 1], Y8[i & 1], srcb, Yb[(i + 1) & 1], Y8[(i + 1) & 1], rp, ep4);
    }
    // PROP_N even -> final bf16 result in Yb0
    mlp2<<<(N_NODES + 255) / 256, 256, 0, stream>>>(Yb0, W2, b2, out);
}

// Round 9
// 853.543 us; speedup vs baseline: 1.0231x; 1.0231x over previous
//
#include <hip/hip_runtime.h>

#define N_NODES 100000
#define N_EDGES 1600000
#define D_IN    256
#define D_HID   64
#define D_OUT   40
#define PROP_N  16

typedef short short8 __attribute__((ext_vector_type(8)));   // 8 bf16 (4 VGPRs)
typedef float f32x4  __attribute__((ext_vector_type(4)));   // MFMA accumulator

// ---- fp8 (OCP e4m3) helpers: HW convert, RNE, saturating ------------------
__device__ __forceinline__ unsigned char f32_to_fp8(float f) {
    int p = __builtin_amdgcn_cvt_pk_fp8_f32(f, f, 0, false);
    return (unsigned char)(p & 0xff);
}
// ---- bf16 helpers (RNE) ---------------------------------------------------
__device__ __forceinline__ unsigned short f32_to_bf16(float f) {
    unsigned int u = __float_as_uint(f);
    unsigned int r = (u + 0x7fffu + ((u >> 16) & 1u)) >> 16;
    return (unsigned short)r;
}
__device__ __forceinline__ unsigned int f32x2_to_bf16x2(float lo, float hi) {
    return (unsigned int)f32_to_bf16(lo) | ((unsigned int)f32_to_bf16(hi) << 16);
}
__device__ __forceinline__ float bf16_f(unsigned short u) {
    return __uint_as_float(((unsigned)u) << 16);
}
// decode packed edge: bits[31:15]=col, bits[14:0]=bf16(val) without sign
__device__ __forceinline__ float edge_val(unsigned p) {
    return __uint_as_float((p & 0x7fffu) << 16);
}
// 4-feature fp8 FMA: b holds 4 fp8 bytes
__device__ __forceinline__ void fma4(float4& a, float v, unsigned b) {
    a.x = fmaf(v, __builtin_amdgcn_cvt_f32_fp8((int)b, 0), a.x);
    a.y = fmaf(v, __builtin_amdgcn_cvt_f32_fp8((int)b, 1), a.y);
    a.z = fmaf(v, __builtin_amdgcn_cvt_f32_fp8((int)b, 2), a.z);
    a.w = fmaf(v, __builtin_amdgcn_cvt_f32_fp8((int)b, 3), a.w);
}

// ---------------------------------------------------------------------------
// Kernel 1: CSR row_ptr from sorted edge_row via binary search.
// ---------------------------------------------------------------------------
__global__ __launch_bounds__(256) void build_rowptr(const int* __restrict__ erow,
                                                    int* __restrict__ rp) {
    int r = blockIdx.x * blockDim.x + threadIdx.x;
    if (r > N_NODES) return;
    int lo = 0, hi = N_EDGES;
    while (lo < hi) {
        int mid = (lo + hi) >> 1;
        if (erow[mid] < r) lo = mid + 1; else hi = mid;
    }
    rp[r] = lo;
}

// ---------------------------------------------------------------------------
// Kernel 1b: pack (col, val) into ONE dword.
//   bits[31:15] = col (100000 < 2^17), bits[14:0] = bf16(val) sans sign.
// ---------------------------------------------------------------------------
__global__ __launch_bounds__(256) void pack_edges4(const int* __restrict__ ecol,
                                                   const float* __restrict__ evalv,
                                                   unsigned* __restrict__ ep4) {
    int i = blockIdx.x * blockDim.x + threadIdx.x;
    if (i >= N_EDGES) return;
    unsigned bf = f32_to_bf16(evalv[i]);
    ep4[i] = ((unsigned)ecol[i] << 15) | (bf & 0x7fffu);
}

// ---------------------------------------------------------------------------
// Kernel 1d: per-row IN-PLACE insertion sort of ep4 by column (p>>15).
// One thread per row, deg ~16 (Poisson). ZERO-traffic gather-locality lever:
// with all 1563 prop blocks co-resident and marching in near-lockstep, sorted
// edge lists make iteration k of every wave gather from the k/deg column
// quantile -> instantaneous gather working set shrinks from all of Y8
// (6.4MB, can't fit 4MiB L2) to a ~1-2MB sliding window (fits). In-degree-16
// line reuse then lands inside the window lifetime -> L2 hits.
// (Summation order changes; error << existing fp8 quantization noise.)
// ---------------------------------------------------------------------------
__global__ __launch_bounds__(256) void sort_edges(const int* __restrict__ rp,
                                                  unsigned* __restrict__ ep4) {
    int r = blockIdx.x * blockDim.x + threadIdx.x;
    if (r >= N_NODES) return;
    const int e0 = rp[r], e1 = rp[r + 1];
    for (int i = e0 + 1; i < e1; ++i) {
        unsigned key = ep4[i];
        int j = i - 1;
        while (j >= e0) {
            unsigned v = ep4[j];
            if ((v >> 15) <= (key >> 15)) break;
            ep4[j + 1] = v;
            --j;
        }
        ep4[j + 1] = key;
    }
}

// ---------------------------------------------------------------------------
// Kernel 1c: W1 [256][64] fp32 -> W1T [64][256] bf16 (for MFMA B-fragments).
// ---------------------------------------------------------------------------
__global__ __launch_bounds__(256) void prep_w1t(const float* __restrict__ W1,
                                                unsigned short* __restrict__ W1T) {
    int i = blockIdx.x * 256 + threadIdx.x;           // 16384 elements
    if (i >= D_IN * D_HID) return;
    int k = i >> 6, n = i & 63;
    W1T[n * 256 + k] = f32_to_bf16(W1[i]);
}

// ---------------------------------------------------------------------------
// Kernel 2 (MFMA): h = x @ W1 + b1. EXACT R4 core — FROZEN. Four structures
// tried (sync loads / reg-preload / K-split / async global_load_lds): all
// land 60-70 us; this one is the 59.5 us floor (per-CU line-service cap).
// Epilogue writes bf16 Y, bf16 src, fp8 Y8.
// ---------------------------------------------------------------------------
__global__ __launch_bounds__(64) void mlp1(const float* __restrict__ x,
                                           const unsigned short* __restrict__ W1T,
                                           const float* __restrict__ b1,
                                           const float* __restrict__ diag,
                                           unsigned short* __restrict__ Yb,
                                           unsigned char* __restrict__ Y08,
                                           unsigned short* __restrict__ srcb) {
    const int lane  = threadIdx.x;
    const int l15   = lane & 15;
    const int quad  = lane >> 4;
    const int mbase = blockIdx.x * 16;      // 6250 * 16 == 100000 exactly

    f32x4 acc[4] = {};
    const float* xrow = x + (size_t)(mbase + l15) * D_IN + quad * 8;

    #pragma unroll
    for (int ks = 0; ks < 8; ++ks) {
        float4 f0 = *(const float4*)(xrow + ks * 32);
        float4 f1 = *(const float4*)(xrow + ks * 32 + 4);
        union { short8 v; unsigned int u[4]; } a;
        a.u[0] = f32x2_to_bf16x2(f0.x, f0.y);
        a.u[1] = f32x2_to_bf16x2(f0.z, f0.w);
        a.u[2] = f32x2_to_bf16x2(f1.x, f1.y);
        a.u[3] = f32x2_to_bf16x2(f1.z, f1.w);

        #pragma unroll
        for (int ct = 0; ct < 4; ++ct) {
            short8 b = *(const short8*)(W1T + (ct * 16 + l15) * 256 + ks * 32 + quad * 8);
            acc[ct] = __builtin_amdgcn_mfma_f32_16x16x32_bf16(a.v, b, acc[ct], 0, 0, 0);
        }
    }

    float bias[4];
    #pragma unroll
    for (int ct = 0; ct < 4; ++ct) bias[ct] = b1[ct * 16 + l15];

    #pragma unroll
    for (int reg = 0; reg < 4; ++reg) {
        const int mr = mbase + quad * 4 + reg;
        const float dg = diag[mr];
        #pragma unroll
        for (int ct = 0; ct < 4; ++ct) {
            const int col = ct * 16 + l15;
            const float h = acc[ct][reg] + bias[ct];
            const size_t idx = (size_t)mr * 64 + col;
            Yb[idx]   = f32_to_bf16(h);
            srcb[idx] = f32_to_bf16(0.5f * dg * h);
            Y08[idx]  = f32_to_fp8(h);
        }
    }
}

// ---------------------------------------------------------------------------
// Kernel 3: one propagation step. EXACT R4 structure (42 us/step known-best).
// R8's nt-load experiment REGRESSED (+7.5us/step): the streams get
// cross-dispatch L2 hits (deterministic block->XCD mapping) — plain cached
// loads are correct. This round's lever is upstream: sorted edge lists.
// ---------------------------------------------------------------------------
__global__ __launch_bounds__(256) void prop_step(const unsigned short* __restrict__ Yb,
                                                 const unsigned char* __restrict__ Y8,
                                                 const unsigned short* __restrict__ srcb,
                                                 unsigned short* __restrict__ Ybo,
                                                 unsigned char* __restrict__ Yo8,
                                                 const int* __restrict__ rp,
                                                 const unsigned* __restrict__ ep4) {
    const int wid  = blockIdx.x * 4 + (threadIdx.x >> 6);   // 25000 waves
    const int lane = threadIdx.x & 63;
    const int g    = lane >> 4;         // row group 0..3
    const int fl   = lane & 15;         // feature-quad index
    const int row  = wid * 4 + g;       // exact: 100000 = 4 * 25000

    const int e0 = rp[row];
    const int e1 = rp[row + 1];

    const size_t fb = (size_t)row * 64 + fl * 4;
    const ushort4 ys4 = *(const ushort4*)(Yb + fb);
    const ushort4 sv4 = *(const ushort4*)(srcb + fb);
    const float4 yself = make_float4(bf16_f(ys4.x), bf16_f(ys4.y),
                                     bf16_f(ys4.z), bf16_f(ys4.w));
    const float4 sv    = make_float4(bf16_f(sv4.x), bf16_f(sv4.y),
                                     bf16_f(sv4.z), bf16_f(sv4.w));
    const unsigned char* Y8f = Y8 + fl * 4;

    float4 acc0 = make_float4(0.f, 0.f, 0.f, 0.f);
    float4 acc1 = acc0, acc2 = acc0, acc3 = acc0;

    int e = e0;
    // scalar head until e is 4-aligned (16B-aligned uint4 loads)
    int ea = (e0 + 3) & ~3;
    if (ea > e1) ea = e1;
    for (; e < ea; ++e) {
        unsigned p = ep4[e];
        unsigned b = *(const unsigned*)(Y8f + ((size_t)(p >> 15) << 6));
        fma4(acc0, edge_val(p), b);
    }
    for (; e + 8 <= e1; e += 8) {
        uint4 pa = *(const uint4*)(ep4 + e);
        uint4 pb = *(const uint4*)(ep4 + e + 4);
        unsigned b0 = *(const unsigned*)(Y8f + ((size_t)(pa.x >> 15) << 6));
        unsigned b1 = *(const unsigned*)(Y8f + ((size_t)(pa.y >> 15) << 6));
        unsigned b2 = *(const unsigned*)(Y8f + ((size_t)(pa.z >> 15) << 6));
        unsigned b3 = *(const unsigned*)(Y8f + ((size_t)(pa.w >> 15) << 6));
        unsigned b4 = *(const unsigned*)(Y8f + ((size_t)(pb.x >> 15) << 6));
        unsigned b5 = *(const unsigned*)(Y8f + ((size_t)(pb.y >> 15) << 6));
        unsigned b6 = *(const unsigned*)(Y8f + ((size_t)(pb.z >> 15) << 6));
        unsigned b7 = *(const unsigned*)(Y8f + ((size_t)(pb.w >> 15) << 6));
        fma4(acc0, edge_val(pa.x), b0);
        fma4(acc1, edge_val(pa.y), b1);
        fma4(acc2, edge_val(pa.z), b2);
        fma4(acc3, edge_val(pa.w), b3);
        fma4(acc0, edge_val(pb.x), b4);
        fma4(acc1, edge_val(pb.y), b5);
        fma4(acc2, edge_val(pb.z), b6);
        fma4(acc3, edge_val(pb.w), b7);
    }
    if (e + 4 <= e1) {
        uint4 pa = *(const uint4*)(ep4 + e);
        unsigned b0 = *(const unsigned*)(Y8f + ((size_t)(pa.x >> 15) << 6));
        unsigned b1 = *(const unsigned*)(Y8f + ((size_t)(pa.y >> 15) << 6));
        unsigned b2 = *(const unsigned*)(Y8f + ((size_t)(pa.z >> 15) << 6));
        unsigned b3 = *(const unsigned*)(Y8f + ((size_t)(pa.w >> 15) << 6));
        fma4(acc0, edge_val(pa.x), b0);
        fma4(acc1, edge_val(pa.y), b1);
        fma4(acc2, edge_val(pa.z), b2);
        fma4(acc3, edge_val(pa.w), b3);
        e += 4;
    }
    for (; e < e1; ++e) {
        unsigned p = ep4[e];
        unsigned b = *(const unsigned*)(Y8f + ((size_t)(p >> 15) << 6));
        fma4(acc0, edge_val(p), b);
    }

    float4 accs;
    accs.x = (acc0.x + acc1.x) + (acc2.x + acc3.x);
    accs.y = (acc0.y + acc1.y) + (acc2.y + acc3.y);
    accs.z = (acc0.z + acc1.z) + (acc2.z + acc3.z);
    accs.w = (acc0.w + acc1.w) + (acc2.w + acc3.w);

    float4 o;
    o.x = fmaf(0.5f, yself.x, fmaf(0.5f, accs.x, sv.x));
    o.y = fmaf(0.5f, yself.y, fmaf(0.5f, accs.y, sv.y));
    o.z = fmaf(0.5f, yself.z, fmaf(0.5f, accs.z, sv.z));
    o.w = fmaf(0.5f, yself.w, fmaf(0.5f, accs.w, sv.w));

    ushort4 ob;
    ob.x = f32_to_bf16(o.x); ob.y = f32_to_bf16(o.y);
    ob.z = f32_to_bf16(o.z); ob.w = f32_to_bf16(o.w);
    *(ushort4*)(Ybo + fb) = ob;
    int pk = __builtin_amdgcn_cvt_pk_fp8_f32(o.x, o.y, 0, false);   // bytes 0,1
    pk     = __builtin_amdgcn_cvt_pk_fp8_f32(o.z, o.w, pk, true);   // bytes 2,3
    *(unsigned*)(Yo8 + fb) = (unsigned)pk;
}

// ---------------------------------------------------------------------------
// Kernel 4: out = relu(Y) @ W2 + b2. Y bf16 (uint4 = 8 features/load).
// ---------------------------------------------------------------------------
__global__ __launch_bounds__(256) void mlp2(const unsigned short* __restrict__ Yb,
                                            const float* __restrict__ W2,
                                            const float* __restrict__ b2,
                                            float* __restrict__ out) {
    __shared__ float W2s[D_HID * D_OUT];
    __shared__ float b2s[D_OUT];
    int tid = threadIdx.x;
    for (int i = tid; i < D_HID * D_OUT; i += 256) W2s[i] = W2[i];
    if (tid < D_OUT) b2s[tid] = b2[tid];
    __syncthreads();

    int n = blockIdx.x * 256 + tid;
    if (n >= N_NODES) return;

    float acc[D_OUT];
    #pragma unroll
    for (int o = 0; o < D_OUT; ++o) acc[o] = b2s[o];

    const uint4* Y4 = (const uint4*)(Yb + (size_t)n * 64);
    #pragma unroll
    for (int k8 = 0; k8 < 8; ++k8) {
        uint4 y = Y4[k8];
        unsigned w[4] = {y.x, y.y, y.z, y.w};
        #pragma unroll
        for (int d = 0; d < 4; ++d) {
            float lo = fmaxf(__uint_as_float((w[d] & 0xffffu) << 16), 0.0f);
            float hi = fmaxf(__uint_as_float(w[d] & 0xffff0000u), 0.0f);
            int klo = k8 * 8 + 2 * d, khi = klo + 1;
            #pragma unroll
            for (int o = 0; o < D_OUT; ++o)
                acc[o] = fmaf(lo, W2s[klo * D_OUT + o], acc[o]);
            #pragma unroll
            for (int o = 0; o < D_OUT; ++o)
                acc[o] = fmaf(hi, W2s[khi * D_OUT + o], acc[o]);
        }
    }

    float4* o4 = (float4*)(out + (size_t)n * D_OUT);
    #pragma unroll
    for (int q = 0; q < 10; ++q)
        o4[q] = make_float4(acc[4 * q], acc[4 * q + 1], acc[4 * q + 2], acc[4 * q + 3]);
}

// ---------------------------------------------------------------------------
extern "C" void kernel_launch(void* const* d_in, const int* in_sizes, int n_in,
                              void* d_out, int out_size, void* d_ws, size_t ws_size,
                              hipStream_t stream) {
    const float* x     = (const float*)d_in[0];
    const int*   erow  = (const int*)  d_in[1];
    const int*   ecol  = (const int*)  d_in[2];
    const float* evalv = (const float*)d_in[3];
    const float* diag  = (const float*)d_in[4];
    const float* W1    = (const float*)d_in[5];
    const float* b1    = (const float*)d_in[6];
    const float* W2    = (const float*)d_in[7];
    const float* b2    = (const float*)d_in[8];
    float* out = (float*)d_out;

    // workspace: Yb0|Yb1|srcb (bf16) | Y08|Y18 (fp8) | ep4 | rp | W1T
    const size_t NV = (size_t)N_NODES * D_HID;
    unsigned short* Yb0  = (unsigned short*)d_ws;
    unsigned short* Yb1  = Yb0 + NV;
    unsigned short* srcb = Yb1 + NV;
    unsigned char*  Y08  = (unsigned char*)(srcb + NV);
    unsigned char*  Y18  = Y08 + NV;
    unsigned*       ep4  = (unsigned*)(Y18 + NV);
    int*            rp   = (int*)(ep4 + N_EDGES);
    unsigned short* W1T  = (unsigned short*)
        (((unsigned long long)(rp + N_NODES + 1) + 15ull) & ~15ull);

    build_rowptr<<<(N_NODES + 1 + 255) / 256, 256, 0, stream>>>(erow, rp);
    pack_edges4<<<(N_EDGES + 255) / 256, 256, 0, stream>>>(ecol, evalv, ep4);
    sort_edges<<<(N_NODES + 255) / 256, 256, 0, stream>>>(rp, ep4);
    prep_w1t<<<(D_IN * D_HID + 255) / 256, 256, 0, stream>>>(W1, W1T);
    mlp1<<<N_NODES / 16, 64, 0, stream>>>(x, W1T, b1, diag, Yb0, Y08, srcb);

    unsigned short* Yb[2] = {Yb0, Yb1};
    unsigned char*  Y8[2] = {Y08, Y18};
    for (int i = 0; i < PROP_N; ++i) {
        prop_step<<<N_NODES / 16, 256, 0, stream>>>(
            Yb[i & 1], Y8[i & 1], srcb, Yb[(i + 1) & 1], Y8[(i + 1) & 1], rp, ep4);
    }
    // PROP_N even -> final bf16 result in Yb0
    mlp2<<<(N_NODES + 255) / 256, 256, 0, stream>>>(Yb0, W2, b2, out);
}

// Round 10
// 759.490 us; speedup vs baseline: 1.1498x; 1.1238x over previous
//
#include <hip/hip_runtime.h>

#define N_NODES 100000
#define N_EDGES 1600000
#define D_IN    256
#define D_HID   64
#define D_OUT   40
#define PROP_N  16

typedef short short8 __attribute__((ext_vector_type(8)));   // 8 bf16 (4 VGPRs)
typedef float f32x4  __attribute__((ext_vector_type(4)));   // MFMA accumulator

// ---- fp8 (OCP e4m3) helpers: HW convert, RNE, saturating ------------------
__device__ __forceinline__ unsigned char f32_to_fp8(float f) {
    int p = __builtin_amdgcn_cvt_pk_fp8_f32(f, f, 0, false);
    return (unsigned char)(p & 0xff);
}
// ---- bf16 helpers (RNE) ---------------------------------------------------
__device__ __forceinline__ unsigned short f32_to_bf16(float f) {
    unsigned int u = __float_as_uint(f);
    unsigned int r = (u + 0x7fffu + ((u >> 16) & 1u)) >> 16;
    return (unsigned short)r;
}
__device__ __forceinline__ unsigned int f32x2_to_bf16x2(float lo, float hi) {
    return (unsigned int)f32_to_bf16(lo) | ((unsigned int)f32_to_bf16(hi) << 16);
}
__device__ __forceinline__ float bf16_f(unsigned short u) {
    return __uint_as_float(((unsigned)u) << 16);
}
// decode packed edge: bits[31:15]=col, bits[14:0]=bf16(val) without sign
__device__ __forceinline__ float edge_val(unsigned p) {
    return __uint_as_float((p & 0x7fffu) << 16);
}
// 4-feature fp8 FMA: b holds 4 fp8 bytes
__device__ __forceinline__ void fma4(float4& a, float v, unsigned b) {
    a.x = fmaf(v, __builtin_amdgcn_cvt_f32_fp8((int)b, 0), a.x);
    a.y = fmaf(v, __builtin_amdgcn_cvt_f32_fp8((int)b, 1), a.y);
    a.z = fmaf(v, __builtin_amdgcn_cvt_f32_fp8((int)b, 2), a.z);
    a.w = fmaf(v, __builtin_amdgcn_cvt_f32_fp8((int)b, 3), a.w);
}

// ---------------------------------------------------------------------------
// Kernel 1: CSR row_ptr from sorted edge_row via binary search.
// ---------------------------------------------------------------------------
__global__ __launch_bounds__(256) void build_rowptr(const int* __restrict__ erow,
                                                    int* __restrict__ rp) {
    int r = blockIdx.x * blockDim.x + threadIdx.x;
    if (r > N_NODES) return;
    int lo = 0, hi = N_EDGES;
    while (lo < hi) {
        int mid = (lo + hi) >> 1;
        if (erow[mid] < r) lo = mid + 1; else hi = mid;
    }
    rp[r] = lo;
}

// ---------------------------------------------------------------------------
// Kernel 1b: pack (col, val) into ONE dword.
//   bits[31:15] = col (100000 < 2^17), bits[14:0] = bf16(val) sans sign.
// ---------------------------------------------------------------------------
__global__ __launch_bounds__(256) void pack_edges4(const int* __restrict__ ecol,
                                                   const float* __restrict__ evalv,
                                                   unsigned* __restrict__ ep4) {
    int i = blockIdx.x * blockDim.x + threadIdx.x;
    if (i >= N_EDGES) return;
    unsigned bf = f32_to_bf16(evalv[i]);
    ep4[i] = ((unsigned)ecol[i] << 15) | (bf & 0x7fffu);
}

// ---------------------------------------------------------------------------
// Kernel 1c: W1 [256][64] fp32 -> W1T [64][256] bf16 (for MFMA B-fragments).
// ---------------------------------------------------------------------------
__global__ __launch_bounds__(256) void prep_w1t(const float* __restrict__ W1,
                                                unsigned short* __restrict__ W1T) {
    int i = blockIdx.x * 256 + threadIdx.x;           // 16384 elements
    if (i >= D_IN * D_HID) return;
    int k = i >> 6, n = i & 63;
    W1T[n * 256 + k] = f32_to_bf16(W1[i]);
}

// ---------------------------------------------------------------------------
// Kernel 2 (MFMA): h = x @ W1 + b1 ; Yb/srcb (bf16), Y8 (fp8).
// CHANGE (last untried mlp1 lever): preload all 16 x-float4s, then ANCHOR
// them with asm volatile value-consumers + sched_barrier(0) so the compiler
// CANNOT sink the loads (R1's preload failed exactly that way: VGPR stayed
// 36, loads sank back to uses). Counters pin mlp1 as outstanding-lines
// bound: ~2 lines/wave in flight x 24 waves/CU x 64B / ~700cyc = 1.8 TB/s
// = measured. 16 lines/wave => ~8x concurrency => HBM-stream regime.
// Math identical to R4 (same values, same MFMA order).
// ---------------------------------------------------------------------------
__global__ __launch_bounds__(64) void mlp1(const float* __restrict__ x,
                                           const unsigned short* __restrict__ W1T,
                                           const float* __restrict__ b1,
                                           const float* __restrict__ diag,
                                           unsigned short* __restrict__ Yb,
                                           unsigned char* __restrict__ Y08,
                                           unsigned short* __restrict__ srcb) {
    const int lane  = threadIdx.x;
    const int l15   = lane & 15;
    const int quad  = lane >> 4;
    const int mbase = blockIdx.x * 16;      // 6250 * 16 == 100000 exactly

    const float* xrow = x + (size_t)(mbase + l15) * D_IN + quad * 8;

    float4 xr[16];
    #pragma unroll
    for (int i = 0; i < 8; ++i) {
        xr[2 * i]     = *(const float4*)(xrow + i * 32);
        xr[2 * i + 1] = *(const float4*)(xrow + i * 32 + 4);
    }
    // Anchor: every loaded value consumed by inline asm -> loads cannot be
    // sunk below this point at IR level; sched_barrier pins MIR scheduling.
    #pragma unroll
    for (int i = 0; i < 16; ++i)
        asm volatile("" :: "v"(xr[i].x), "v"(xr[i].y), "v"(xr[i].z), "v"(xr[i].w));
    __builtin_amdgcn_sched_barrier(0);

    f32x4 acc[4] = {};
    #pragma unroll
    for (int ks = 0; ks < 8; ++ks) {
        union { short8 v; unsigned int u[4]; } a;
        a.u[0] = f32x2_to_bf16x2(xr[2 * ks].x, xr[2 * ks].y);
        a.u[1] = f32x2_to_bf16x2(xr[2 * ks].z, xr[2 * ks].w);
        a.u[2] = f32x2_to_bf16x2(xr[2 * ks + 1].x, xr[2 * ks + 1].y);
        a.u[3] = f32x2_to_bf16x2(xr[2 * ks + 1].z, xr[2 * ks + 1].w);

        #pragma unroll
        for (int ct = 0; ct < 4; ++ct) {
            short8 b = *(const short8*)(W1T + (ct * 16 + l15) * 256 + ks * 32 + quad * 8);
            acc[ct] = __builtin_amdgcn_mfma_f32_16x16x32_bf16(a.v, b, acc[ct], 0, 0, 0);
        }
    }

    float bias[4];
    #pragma unroll
    for (int ct = 0; ct < 4; ++ct) bias[ct] = b1[ct * 16 + l15];

    #pragma unroll
    for (int reg = 0; reg < 4; ++reg) {
        const int mr = mbase + quad * 4 + reg;
        const float dg = diag[mr];
        #pragma unroll
        for (int ct = 0; ct < 4; ++ct) {
            const int col = ct * 16 + l15;
            const float h = acc[ct][reg] + bias[ct];
            const size_t idx = (size_t)mr * 64 + col;
            Yb[idx]   = f32_to_bf16(h);
            srcb[idx] = f32_to_bf16(0.5f * dg * h);
            Y08[idx]  = f32_to_fp8(h);
        }
    }
}

// ---------------------------------------------------------------------------
// Kernel 3: one propagation step. EXACT R4 structure (42 us/step floor).
// Seven levers tried: request-width (-13%), ILP depth (null), feature-split
// (worse), bf16 streams (-10%), column-split (worse), nt-loads (worse),
// column-sort (null). Remaining cost = line-count x ~13.9 cyc/line/CU with
// gathers at their 1-line/edge floor. Structural floor for this design.
// ---------------------------------------------------------------------------
__global__ __launch_bounds__(256) void prop_step(const unsigned short* __restrict__ Yb,
                                                 const unsigned char* __restrict__ Y8,
                                                 const unsigned short* __restrict__ srcb,
                                                 unsigned short* __restrict__ Ybo,
                                                 unsigned char* __restrict__ Yo8,
                                                 const int* __restrict__ rp,
                                                 const unsigned* __restrict__ ep4) {
    const int wid  = blockIdx.x * 4 + (threadIdx.x >> 6);   // 25000 waves
    const int lane = threadIdx.x & 63;
    const int g    = lane >> 4;         // row group 0..3
    const int fl   = lane & 15;         // feature-quad index
    const int row  = wid * 4 + g;       // exact: 100000 = 4 * 25000

    const int e0 = rp[row];
    const int e1 = rp[row + 1];

    const size_t fb = (size_t)row * 64 + fl * 4;
    const ushort4 ys4 = *(const ushort4*)(Yb + fb);
    const ushort4 sv4 = *(const ushort4*)(srcb + fb);
    const float4 yself = make_float4(bf16_f(ys4.x), bf16_f(ys4.y),
                                     bf16_f(ys4.z), bf16_f(ys4.w));
    const float4 sv    = make_float4(bf16_f(sv4.x), bf16_f(sv4.y),
                                     bf16_f(sv4.z), bf16_f(sv4.w));
    const unsigned char* Y8f = Y8 + fl * 4;

    float4 acc0 = make_float4(0.f, 0.f, 0.f, 0.f);
    float4 acc1 = acc0, acc2 = acc0, acc3 = acc0;

    int e = e0;
    // scalar head until e is 4-aligned (16B-aligned uint4 loads)
    int ea = (e0 + 3) & ~3;
    if (ea > e1) ea = e1;
    for (; e < ea; ++e) {
        unsigned p = ep4[e];
        unsigned b = *(const unsigned*)(Y8f + ((size_t)(p >> 15) << 6));
        fma4(acc0, edge_val(p), b);
    }
    for (; e + 8 <= e1; e += 8) {
        uint4 pa = *(const uint4*)(ep4 + e);
        uint4 pb = *(const uint4*)(ep4 + e + 4);
        unsigned b0 = *(const unsigned*)(Y8f + ((size_t)(pa.x >> 15) << 6));
        unsigned b1 = *(const unsigned*)(Y8f + ((size_t)(pa.y >> 15) << 6));
        unsigned b2 = *(const unsigned*)(Y8f + ((size_t)(pa.z >> 15) << 6));
        unsigned b3 = *(const unsigned*)(Y8f + ((size_t)(pa.w >> 15) << 6));
        unsigned b4 = *(const unsigned*)(Y8f + ((size_t)(pb.x >> 15) << 6));
        unsigned b5 = *(const unsigned*)(Y8f + ((size_t)(pb.y >> 15) << 6));
        unsigned b6 = *(const unsigned*)(Y8f + ((size_t)(pb.z >> 15) << 6));
        unsigned b7 = *(const unsigned*)(Y8f + ((size_t)(pb.w >> 15) << 6));
        fma4(acc0, edge_val(pa.x), b0);
        fma4(acc1, edge_val(pa.y), b1);
        fma4(acc2, edge_val(pa.z), b2);
        fma4(acc3, edge_val(pa.w), b3);
        fma4(acc0, edge_val(pb.x), b4);
        fma4(acc1, edge_val(pb.y), b5);
        fma4(acc2, edge_val(pb.z), b6);
        fma4(acc3, edge_val(pb.w), b7);
    }
    if (e + 4 <= e1) {
        uint4 pa = *(const uint4*)(ep4 + e);
        unsigned b0 = *(const unsigned*)(Y8f + ((size_t)(pa.x >> 15) << 6));
        unsigned b1 = *(const unsigned*)(Y8f + ((size_t)(pa.y >> 15) << 6));
        unsigned b2 = *(const unsigned*)(Y8f + ((size_t)(pa.z >> 15) << 6));
        unsigned b3 = *(const unsigned*)(Y8f + ((size_t)(pa.w >> 15) << 6));
        fma4(acc0, edge_val(pa.x), b0);
        fma4(acc1, edge_val(pa.y), b1);
        fma4(acc2, edge_val(pa.z), b2);
        fma4(acc3, edge_val(pa.w), b3);
        e += 4;
    }
    for (; e < e1; ++e) {
        unsigned p = ep4[e];
        unsigned b = *(const unsigned*)(Y8f + ((size_t)(p >> 15) << 6));
        fma4(acc0, edge_val(p), b);
    }

    float4 accs;
    accs.x = (acc0.x + acc1.x) + (acc2.x + acc3.x);
    accs.y = (acc0.y + acc1.y) + (acc2.y + acc3.y);
    accs.z = (acc0.z + acc1.z) + (acc2.z + acc3.z);
    accs.w = (acc0.w + acc1.w) + (acc2.w + acc3.w);

    float4 o;
    o.x = fmaf(0.5f, yself.x, fmaf(0.5f, accs.x, sv.x));
    o.y = fmaf(0.5f, yself.y, fmaf(0.5f, accs.y, sv.y));
    o.z = fmaf(0.5f, yself.z, fmaf(0.5f, accs.z, sv.z));
    o.w = fmaf(0.5f, yself.w, fmaf(0.5f, accs.w, sv.w));

    ushort4 ob;
    ob.x = f32_to_bf16(o.x); ob.y = f32_to_bf16(o.y);
    ob.z = f32_to_bf16(o.z); ob.w = f32_to_bf16(o.w);
    *(ushort4*)(Ybo + fb) = ob;
    int pk = __builtin_amdgcn_cvt_pk_fp8_f32(o.x, o.y, 0, false);   // bytes 0,1
    pk     = __builtin_amdgcn_cvt_pk_fp8_f32(o.z, o.w, pk, true);   // bytes 2,3
    *(unsigned*)(Yo8 + fb) = (unsigned)pk;
}

// ---------------------------------------------------------------------------
// Kernel 4: out = relu(Y) @ W2 + b2. Y bf16 (uint4 = 8 features/load).
// ---------------------------------------------------------------------------
__global__ __launch_bounds__(256) void mlp2(const unsigned short* __restrict__ Yb,
                                            const float* __restrict__ W2,
                                            const float* __restrict__ b2,
                                            float* __restrict__ out) {
    __shared__ float W2s[D_HID * D_OUT];
    __shared__ float b2s[D_OUT];
    int tid = threadIdx.x;
    for (int i = tid; i < D_HID * D_OUT; i += 256) W2s[i] = W2[i];
    if (tid < D_OUT) b2s[tid] = b2[tid];
    __syncthreads();

    int n = blockIdx.x * 256 + tid;
    if (n >= N_NODES) return;

    float acc[D_OUT];
    #pragma unroll
    for (int o = 0; o < D_OUT; ++o) acc[o] = b2s[o];

    const uint4* Y4 = (const uint4*)(Yb + (size_t)n * 64);
    #pragma unroll
    for (int k8 = 0; k8 < 8; ++k8) {
        uint4 y = Y4[k8];
        unsigned w[4] = {y.x, y.y, y.z, y.w};
        #pragma unroll
        for (int d = 0; d < 4; ++d) {
            float lo = fmaxf(__uint_as_float((w[d] & 0xffffu) << 16), 0.0f);
            float hi = fmaxf(__uint_as_float(w[d] & 0xffff0000u), 0.0f);
            int klo = k8 * 8 + 2 * d, khi = klo + 1;
            #pragma unroll
            for (int o = 0; o < D_OUT; ++o)
                acc[o] = fmaf(lo, W2s[klo * D_OUT + o], acc[o]);
            #pragma unroll
            for (int o = 0; o < D_OUT; ++o)
                acc[o] = fmaf(hi, W2s[khi * D_OUT + o], acc[o]);
        }
    }

    float4* o4 = (float4*)(out + (size_t)n * D_OUT);
    #pragma unroll
    for (int q = 0; q < 10; ++q)
        o4[q] = make_float4(acc[4 * q], acc[4 * q + 1], acc[4 * q + 2], acc[4 * q + 3]);
}

// ---------------------------------------------------------------------------
extern "C" void kernel_launch(void* const* d_in, const int* in_sizes, int n_in,
                              void* d_out, int out_size, void* d_ws, size_t ws_size,
                              hipStream_t stream) {
    const float* x     = (const float*)d_in[0];
    const int*   erow  = (const int*)  d_in[1];
    const int*   ecol  = (const int*)  d_in[2];
    const float* evalv = (const float*)d_in[3];
    const float* diag  = (const float*)d_in[4];
    const float* W1    = (const float*)d_in[5];
    const float* b1    = (const float*)d_in[6];
    const float* W2    = (const float*)d_in[7];
    const float* b2    = (const float*)d_in[8];
    float* out = (float*)d_out;

    // workspace: Yb0|Yb1|srcb (bf16) | Y08|Y18 (fp8) | ep4 | rp | W1T
    const size_t NV = (size_t)N_NODES * D_HID;
    unsigned short* Yb0  = (unsigned short*)d_ws;
    unsigned short* Yb1  = Yb0 + NV;
    unsigned short* srcb = Yb1 + NV;
    unsigned char*  Y08  = (unsigned char*)(srcb + NV);
    unsigned char*  Y18  = Y08 + NV;
    unsigned*       ep4  = (unsigned*)(Y18 + NV);
    int*            rp   = (int*)(ep4 + N_EDGES);
    unsigned short* W1T  = (unsigned short*)
        (((unsigned long long)(rp + N_NODES + 1) + 15ull) & ~15ull);

    build_rowptr<<<(N_NODES + 1 + 255) / 256, 256, 0, stream>>>(erow, rp);
    pack_edges4<<<(N_EDGES + 255) / 256, 256, 0, stream>>>(ecol, evalv, ep4);
    prep_w1t<<<(D_IN * D_HID + 255) / 256, 256, 0, stream>>>(W1, W1T);
    mlp1<<<N_NODES / 16, 64, 0, stream>>>(x, W1T, b1, diag, Yb0, Y08, srcb);

    unsigned short* Yb[2] = {Yb0, Yb1};
    unsigned char*  Y8[2] = {Y08, Y18};
    for (int i = 0; i < PROP_N; ++i) {
        prop_step<<<N_NODES / 16, 256, 0, stream>>>(
            Yb[i & 1], Y8[i & 1], srcb, Yb[(i + 1) & 1], Y8[(i + 1) & 1], rp, ep4);
    }
    // PROP_N even -> final bf16 result in Yb0
    mlp2<<<(N_NODES + 255) / 256, 256, 0, stream>>>(Yb0, W2, b2, out);
}

// Round 11
// 751.423 us; speedup vs baseline: 1.1622x; 1.0107x over previous
//
#include <hip/hip_runtime.h>

#define N_NODES 100000
#define N_EDGES 1600000
#define D_IN    256
#define D_HID   64
#define D_OUT   40
#define PROP_N  16

typedef short short8 __attribute__((ext_vector_type(8)));   // 8 bf16 (4 VGPRs)
typedef float f32x4  __attribute__((ext_vector_type(4)));   // MFMA accumulator

// ---- fp8 (OCP e4m3) helpers: HW convert, RNE, saturating ------------------
__device__ __forceinline__ unsigned char f32_to_fp8(float f) {
    int p = __builtin_amdgcn_cvt_pk_fp8_f32(f, f, 0, false);
    return (unsigned char)(p & 0xff);
}
// ---- bf16 helpers (RNE) ---------------------------------------------------
__device__ __forceinline__ unsigned short f32_to_bf16(float f) {
    unsigned int u = __float_as_uint(f);
    unsigned int r = (u + 0x7fffu + ((u >> 16) & 1u)) >> 16;
    return (unsigned short)r;
}
__device__ __forceinline__ unsigned int f32x2_to_bf16x2(float lo, float hi) {
    return (unsigned int)f32_to_bf16(lo) | ((unsigned int)f32_to_bf16(hi) << 16);
}
__device__ __forceinline__ float bf16_f(unsigned short u) {
    return __uint_as_float(((unsigned)u) << 16);
}
// decode packed edge: bits[31:15]=col, bits[14:0]=bf16(val) without sign
__device__ __forceinline__ float edge_val(unsigned p) {
    return __uint_as_float((p & 0x7fffu) << 16);
}
// 4-feature fp8 FMA: b holds 4 fp8 bytes
__device__ __forceinline__ void fma4(float4& a, float v, unsigned b) {
    a.x = fmaf(v, __builtin_amdgcn_cvt_f32_fp8((int)b, 0), a.x);
    a.y = fmaf(v, __builtin_amdgcn_cvt_f32_fp8((int)b, 1), a.y);
    a.z = fmaf(v, __builtin_amdgcn_cvt_f32_fp8((int)b, 2), a.z);
    a.w = fmaf(v, __builtin_amdgcn_cvt_f32_fp8((int)b, 3), a.w);
}

// ---------------------------------------------------------------------------
// Kernel 1: CSR row_ptr from sorted edge_row via binary search.
// ---------------------------------------------------------------------------
__global__ __launch_bounds__(256) void build_rowptr(const int* __restrict__ erow,
                                                    int* __restrict__ rp) {
    int r = blockIdx.x * blockDim.x + threadIdx.x;
    if (r > N_NODES) return;
    int lo = 0, hi = N_EDGES;
    while (lo < hi) {
        int mid = (lo + hi) >> 1;
        if (erow[mid] < r) lo = mid + 1; else hi = mid;
    }
    rp[r] = lo;
}

// ---------------------------------------------------------------------------
// Kernel 1b: pack (col, val) into ONE dword.
//   bits[31:15] = col (100000 < 2^17), bits[14:0] = bf16(val) sans sign.
// ---------------------------------------------------------------------------
__global__ __launch_bounds__(256) void pack_edges4(const int* __restrict__ ecol,
                                                   const float* __restrict__ evalv,
                                                   unsigned* __restrict__ ep4) {
    int i = blockIdx.x * blockDim.x + threadIdx.x;
    if (i >= N_EDGES) return;
    unsigned bf = f32_to_bf16(evalv[i]);
    ep4[i] = ((unsigned)ecol[i] << 15) | (bf & 0x7fffu);
}

// ---------------------------------------------------------------------------
// Kernel 1c: W1 [256][64] fp32 -> W1T [64][256] bf16 (for MFMA B-fragments).
// ---------------------------------------------------------------------------
__global__ __launch_bounds__(256) void prep_w1t(const float* __restrict__ W1,
                                                unsigned short* __restrict__ W1T) {
    int i = blockIdx.x * 256 + threadIdx.x;           // 16384 elements
    if (i >= D_IN * D_HID) return;
    int k = i >> 6, n = i & 63;
    W1T[n * 256 + k] = f32_to_bf16(W1[i]);
}

// ---------------------------------------------------------------------------
// Kernel 2 (MFMA): h = x @ W1 + b1. EXACT R4 core — FINAL. Five structures
// tried (sync@uses / reg-preload / K-split / async global_load_lds /
// anchored-preload): 59.5 us is the floor. R10 proved throughput tracks
// occupancy, not per-wave in-flight lines (4x lines @ 27% occ -> BW DOWN) —
// latency-bound at max occupancy is this kernel's regime.
// Epilogue writes bf16 Y, bf16 src, fp8 Y8.
// ---------------------------------------------------------------------------
__global__ __launch_bounds__(64) void mlp1(const float* __restrict__ x,
                                           const unsigned short* __restrict__ W1T,
                                           const float* __restrict__ b1,
                                           const float* __restrict__ diag,
                                           unsigned short* __restrict__ Yb,
                                           unsigned char* __restrict__ Y08,
                                           unsigned short* __restrict__ srcb) {
    const int lane  = threadIdx.x;
    const int l15   = lane & 15;
    const int quad  = lane >> 4;
    const int mbase = blockIdx.x * 16;      // 6250 * 16 == 100000 exactly

    f32x4 acc[4] = {};
    const float* xrow = x + (size_t)(mbase + l15) * D_IN + quad * 8;

    #pragma unroll
    for (int ks = 0; ks < 8; ++ks) {
        float4 f0 = *(const float4*)(xrow + ks * 32);
        float4 f1 = *(const float4*)(xrow + ks * 32 + 4);
        union { short8 v; unsigned int u[4]; } a;
        a.u[0] = f32x2_to_bf16x2(f0.x, f0.y);
        a.u[1] = f32x2_to_bf16x2(f0.z, f0.w);
        a.u[2] = f32x2_to_bf16x2(f1.x, f1.y);
        a.u[3] = f32x2_to_bf16x2(f1.z, f1.w);

        #pragma unroll
        for (int ct = 0; ct < 4; ++ct) {
            short8 b = *(const short8*)(W1T + (ct * 16 + l15) * 256 + ks * 32 + quad * 8);
            acc[ct] = __builtin_amdgcn_mfma_f32_16x16x32_bf16(a.v, b, acc[ct], 0, 0, 0);
        }
    }

    float bias[4];
    #pragma unroll
    for (int ct = 0; ct < 4; ++ct) bias[ct] = b1[ct * 16 + l15];

    #pragma unroll
    for (int reg = 0; reg < 4; ++reg) {
        const int mr = mbase + quad * 4 + reg;
        const float dg = diag[mr];
        #pragma unroll
        for (int ct = 0; ct < 4; ++ct) {
            const int col = ct * 16 + l15;
            const float h = acc[ct][reg] + bias[ct];
            const size_t idx = (size_t)mr * 64 + col;
            Yb[idx]   = f32_to_bf16(h);
            srcb[idx] = f32_to_bf16(0.5f * dg * h);
            Y08[idx]  = f32_to_fp8(h);
        }
    }
}

// ---------------------------------------------------------------------------
// Kernel 3: one propagation step. EXACT R4 structure (42 us/step floor).
// Seven levers tried: request-width (-13%), ILP depth (null), feature-split
// (worse), bf16 streams (-10%), column-split (worse), nt-loads (worse),
// column-sort (null). Remaining cost = line-count x ~13.9 cyc/line/CU with
// gathers at their 1-line/edge floor. Structural floor for this design.
// ---------------------------------------------------------------------------
__global__ __launch_bounds__(256) void prop_step(const unsigned short* __restrict__ Yb,
                                                 const unsigned char* __restrict__ Y8,
                                                 const unsigned short* __restrict__ srcb,
                                                 unsigned short* __restrict__ Ybo,
                                                 unsigned char* __restrict__ Yo8,
                                                 const int* __restrict__ rp,
                                                 const unsigned* __restrict__ ep4) {
    const int wid  = blockIdx.x * 4 + (threadIdx.x >> 6);   // 25000 waves
    const int lane = threadIdx.x & 63;
    const int g    = lane >> 4;         // row group 0..3
    const int fl   = lane & 15;         // feature-quad index
    const int row  = wid * 4 + g;       // exact: 100000 = 4 * 25000

    const int e0 = rp[row];
    const int e1 = rp[row + 1];

    const size_t fb = (size_t)row * 64 + fl * 4;
    const ushort4 ys4 = *(const ushort4*)(Yb + fb);
    const ushort4 sv4 = *(const ushort4*)(srcb + fb);
    const float4 yself = make_float4(bf16_f(ys4.x), bf16_f(ys4.y),
                                     bf16_f(ys4.z), bf16_f(ys4.w));
    const float4 sv    = make_float4(bf16_f(sv4.x), bf16_f(sv4.y),
                                     bf16_f(sv4.z), bf16_f(sv4.w));
    const unsigned char* Y8f = Y8 + fl * 4;

    float4 acc0 = make_float4(0.f, 0.f, 0.f, 0.f);
    float4 acc1 = acc0, acc2 = acc0, acc3 = acc0;

    int e = e0;
    // scalar head until e is 4-aligned (16B-aligned uint4 loads)
    int ea = (e0 + 3) & ~3;
    if (ea > e1) ea = e1;
    for (; e < ea; ++e) {
        unsigned p = ep4[e];
        unsigned b = *(const unsigned*)(Y8f + ((size_t)(p >> 15) << 6));
        fma4(acc0, edge_val(p), b);
    }
    for (; e + 8 <= e1; e += 8) {
        uint4 pa = *(const uint4*)(ep4 + e);
        uint4 pb = *(const uint4*)(ep4 + e + 4);
        unsigned b0 = *(const unsigned*)(Y8f + ((size_t)(pa.x >> 15) << 6));
        unsigned b1 = *(const unsigned*)(Y8f + ((size_t)(pa.y >> 15) << 6));
        unsigned b2 = *(const unsigned*)(Y8f + ((size_t)(pa.z >> 15) << 6));
        unsigned b3 = *(const unsigned*)(Y8f + ((size_t)(pa.w >> 15) << 6));
        unsigned b4 = *(const unsigned*)(Y8f + ((size_t)(pb.x >> 15) << 6));
        unsigned b5 = *(const unsigned*)(Y8f + ((size_t)(pb.y >> 15) << 6));
        unsigned b6 = *(const unsigned*)(Y8f + ((size_t)(pb.z >> 15) << 6));
        unsigned b7 = *(const unsigned*)(Y8f + ((size_t)(pb.w >> 15) << 6));
        fma4(acc0, edge_val(pa.x), b0);
        fma4(acc1, edge_val(pa.y), b1);
        fma4(acc2, edge_val(pa.z), b2);
        fma4(acc3, edge_val(pa.w), b3);
        fma4(acc0, edge_val(pb.x), b4);
        fma4(acc1, edge_val(pb.y), b5);
        fma4(acc2, edge_val(pb.z), b6);
        fma4(acc3, edge_val(pb.w), b7);
    }
    if (e + 4 <= e1) {
        uint4 pa = *(const uint4*)(ep4 + e);
        unsigned b0 = *(const unsigned*)(Y8f + ((size_t)(pa.x >> 15) << 6));
        unsigned b1 = *(const unsigned*)(Y8f + ((size_t)(pa.y >> 15) << 6));
        unsigned b2 = *(const unsigned*)(Y8f + ((size_t)(pa.z >> 15) << 6));
        unsigned b3 = *(const unsigned*)(Y8f + ((size_t)(pa.w >> 15) << 6));
        fma4(acc0, edge_val(pa.x), b0);
        fma4(acc1, edge_val(pa.y), b1);
        fma4(acc2, edge_val(pa.z), b2);
        fma4(acc3, edge_val(pa.w), b3);
        e += 4;
    }
    for (; e < e1; ++e) {
        unsigned p = ep4[e];
        unsigned b = *(const unsigned*)(Y8f + ((size_t)(p >> 15) << 6));
        fma4(acc0, edge_val(p), b);
    }

    float4 accs;
    accs.x = (acc0.x + acc1.x) + (acc2.x + acc3.x);
    accs.y = (acc0.y + acc1.y) + (acc2.y + acc3.y);
    accs.z = (acc0.z + acc1.z) + (acc2.z + acc3.z);
    accs.w = (acc0.w + acc1.w) + (acc2.w + acc3.w);

    float4 o;
    o.x = fmaf(0.5f, yself.x, fmaf(0.5f, accs.x, sv.x));
    o.y = fmaf(0.5f, yself.y, fmaf(0.5f, accs.y, sv.y));
    o.z = fmaf(0.5f, yself.z, fmaf(0.5f, accs.z, sv.z));
    o.w = fmaf(0.5f, yself.w, fmaf(0.5f, accs.w, sv.w));

    ushort4 ob;
    ob.x = f32_to_bf16(o.x); ob.y = f32_to_bf16(o.y);
    ob.z = f32_to_bf16(o.z); ob.w = f32_to_bf16(o.w);
    *(ushort4*)(Ybo + fb) = ob;
    int pk = __builtin_amdgcn_cvt_pk_fp8_f32(o.x, o.y, 0, false);   // bytes 0,1
    pk     = __builtin_amdgcn_cvt_pk_fp8_f32(o.z, o.w, pk, true);   // bytes 2,3
    *(unsigned*)(Yo8 + fb) = (unsigned)pk;
}

// ---------------------------------------------------------------------------
// Kernel 4: out = relu(Y) @ W2 + b2. Y bf16 (uint4 = 8 features/load).
// ---------------------------------------------------------------------------
__global__ __launch_bounds__(256) void mlp2(const unsigned short* __restrict__ Yb,
                                            const float* __restrict__ W2,
                                            const float* __restrict__ b2,
                                            float* __restrict__ out) {
    __shared__ float W2s[D_HID * D_OUT];
    __shared__ float b2s[D_OUT];
    int tid = threadIdx.x;
    for (int i = tid; i < D_HID * D_OUT; i += 256) W2s[i] = W2[i];
    if (tid < D_OUT) b2s[tid] = b2[tid];
    __syncthreads();

    int n = blockIdx.x * 256 + tid;
    if (n >= N_NODES) return;

    float acc[D_OUT];
    #pragma unroll
    for (int o = 0; o < D_OUT; ++o) acc[o] = b2s[o];

    const uint4* Y4 = (const uint4*)(Yb + (size_t)n * 64);
    #pragma unroll
    for (int k8 = 0; k8 < 8; ++k8) {
        uint4 y = Y4[k8];
        unsigned w[4] = {y.x, y.y, y.z, y.w};
        #pragma unroll
        for (int d = 0; d < 4; ++d) {
            float lo = fmaxf(__uint_as_float((w[d] & 0xffffu) << 16), 0.0f);
            float hi = fmaxf(__uint_as_float(w[d] & 0xffff0000u), 0.0f);
            int klo = k8 * 8 + 2 * d, khi = klo + 1;
            #pragma unroll
            for (int o = 0; o < D_OUT; ++o)
                acc[o] = fmaf(lo, W2s[klo * D_OUT + o], acc[o]);
            #pragma unroll
            for (int o = 0; o < D_OUT; ++o)
                acc[o] = fmaf(hi, W2s[khi * D_OUT + o], acc[o]);
        }
    }

    float4* o4 = (float4*)(out + (size_t)n * D_OUT);
    #pragma unroll
    for (int q = 0; q < 10; ++q)
        o4[q] = make_float4(acc[4 * q], acc[4 * q + 1], acc[4 * q + 2], acc[4 * q + 3]);
}

// ---------------------------------------------------------------------------
extern "C" void kernel_launch(void* const* d_in, const int* in_sizes, int n_in,
                              void* d_out, int out_size, void* d_ws, size_t ws_size,
                              hipStream_t stream) {
    const float* x     = (const float*)d_in[0];
    const int*   erow  = (const int*)  d_in[1];
    const int*   ecol  = (const int*)  d_in[2];
    const float* evalv = (const float*)d_in[3];
    const float* diag  = (const float*)d_in[4];
    const float* W1    = (const float*)d_in[5];
    const float* b1    = (const float*)d_in[6];
    const float* W2    = (const float*)d_in[7];
    const float* b2    = (const float*)d_in[8];
    float* out = (float*)d_out;

    // workspace: Yb0|Yb1|srcb (bf16) | Y08|Y18 (fp8) | ep4 | rp | W1T
    const size_t NV = (size_t)N_NODES * D_HID;
    unsigned short* Yb0  = (unsigned short*)d_ws;
    unsigned short* Yb1  = Yb0 + NV;
    unsigned short* srcb = Yb1 + NV;
    unsigned char*  Y08  = (unsigned char*)(srcb + NV);
    unsigned char*  Y18  = Y08 + NV;
    unsigned*       ep4  = (unsigned*)(Y18 + NV);
    int*            rp   = (int*)(ep4 + N_EDGES);
    unsigned short* W1T  = (unsigned short*)
        (((unsigned long long)(rp + N_NODES + 1) + 15ull) & ~15ull);

    build_rowptr<<<(N_NODES + 1 + 255) / 256, 256, 0, stream>>>(erow, rp);
    pack_edges4<<<(N_EDGES + 255) / 256, 256, 0, stream>>>(ecol, evalv, ep4);
    prep_w1t<<<(D_IN * D_HID + 255) / 256, 256, 0, stream>>>(W1, W1T);
    mlp1<<<N_NODES / 16, 64, 0, stream>>>(x, W1T, b1, diag, Yb0, Y08, srcb);

    unsigned short* Yb[2] = {Yb0, Yb1};
    unsigned char*  Y8[2] = {Y08, Y18};
    for (int i = 0; i < PROP_N; ++i) {
        prop_step<<<N_NODES / 16, 256, 0, stream>>>(
            Yb[i & 1], Y8[i & 1], srcb, Yb[(i + 1) & 1], Y8[(i + 1) & 1], rp, ep4);
    }
    // PROP_N even -> final bf16 result in Yb0
    mlp2<<<(N_NODES + 255) / 256, 256, 0, stream>>>(Yb0, W2, b2, out);
}

// Round 12
// 744.670 us; speedup vs baseline: 1.1727x; 1.0091x over previous
//
#include <hip/hip_runtime.h>

#define N_NODES 100000
#define N_EDGES 1600000
#define D_IN    256
#define D_HID   64
#define D_OUT   40
#define PROP_N  16

typedef short short8 __attribute__((ext_vector_type(8)));   // 8 bf16 (4 VGPRs)
typedef float f32x4  __attribute__((ext_vector_type(4)));   // MFMA accumulator

// ---- fp8 (OCP e4m3) helpers: HW convert, RNE, saturating ------------------
__device__ __forceinline__ unsigned char f32_to_fp8(float f) {
    int p = __builtin_amdgcn_cvt_pk_fp8_f32(f, f, 0, false);
    return (unsigned char)(p & 0xff);
}
// ---- bf16 helpers (RNE) ---------------------------------------------------
__device__ __forceinline__ unsigned short f32_to_bf16(float f) {
    unsigned int u = __float_as_uint(f);
    unsigned int r = (u + 0x7fffu + ((u >> 16) & 1u)) >> 16;
    return (unsigned short)r;
}
__device__ __forceinline__ unsigned int f32x2_to_bf16x2(float lo, float hi) {
    return (unsigned int)f32_to_bf16(lo) | ((unsigned int)f32_to_bf16(hi) << 16);
}
__device__ __forceinline__ float bf16_f(unsigned short u) {
    return __uint_as_float(((unsigned)u) << 16);
}
// decode packed edge: bits[31:15]=col, bits[14:0]=bf16(val) without sign
__device__ __forceinline__ float edge_val(unsigned p) {
    return __uint_as_float((p & 0x7fffu) << 16);
}
// 4-feature fp8 FMA: b holds 4 fp8 bytes
__device__ __forceinline__ void fma4(float4& a, float v, unsigned b) {
    a.x = fmaf(v, __builtin_amdgcn_cvt_f32_fp8((int)b, 0), a.x);
    a.y = fmaf(v, __builtin_amdgcn_cvt_f32_fp8((int)b, 1), a.y);
    a.z = fmaf(v, __builtin_amdgcn_cvt_f32_fp8((int)b, 2), a.z);
    a.w = fmaf(v, __builtin_amdgcn_cvt_f32_fp8((int)b, 3), a.w);
}

// ---------------------------------------------------------------------------
// Kernel 1: CSR row_ptr from sorted edge_row via binary search.
// ---------------------------------------------------------------------------
__global__ __launch_bounds__(256) void build_rowptr(const int* __restrict__ erow,
                                                    int* __restrict__ rp) {
    int r = blockIdx.x * blockDim.x + threadIdx.x;
    if (r > N_NODES) return;
    int lo = 0, hi = N_EDGES;
    while (lo < hi) {
        int mid = (lo + hi) >> 1;
        if (erow[mid] < r) lo = mid + 1; else hi = mid;
    }
    rp[r] = lo;
}

// ---------------------------------------------------------------------------
// Kernel 1b: pack (col, val) into ONE dword.
//   bits[31:15] = col (100000 < 2^17), bits[14:0] = bf16(val) sans sign.
// ---------------------------------------------------------------------------
__global__ __launch_bounds__(256) void pack_edges4(const int* __restrict__ ecol,
                                                   const float* __restrict__ evalv,
                                                   unsigned* __restrict__ ep4) {
    int i = blockIdx.x * blockDim.x + threadIdx.x;
    if (i >= N_EDGES) return;
    unsigned bf = f32_to_bf16(evalv[i]);
    ep4[i] = ((unsigned)ecol[i] << 15) | (bf & 0x7fffu);
}

// ---------------------------------------------------------------------------
// Kernel 1c: W1 [256][64] fp32 -> W1T [64][256] bf16 (for MFMA B-fragments).
// ---------------------------------------------------------------------------
__global__ __launch_bounds__(256) void prep_w1t(const float* __restrict__ W1,
                                                unsigned short* __restrict__ W1T) {
    int i = blockIdx.x * 256 + threadIdx.x;           // 16384 elements
    if (i >= D_IN * D_HID) return;
    int k = i >> 6, n = i & 63;
    W1T[n * 256 + k] = f32_to_bf16(W1[i]);
}

// ---------------------------------------------------------------------------
// Kernel 1e: W2 [64][40] fp32 -> hi/lo bf16 pair, MFMA-B layout [48][64]
// (cols padded 40->48 with zeros). W2 = hi + lo to ~2^-17 relative =>
// the bf16 MFMA path adds NO observable output error (split-precision).
// ---------------------------------------------------------------------------
__global__ __launch_bounds__(256) void prep_w2t(const float* __restrict__ W2,
                                                unsigned short* __restrict__ W2Th,
                                                unsigned short* __restrict__ W2Tl) {
    int i = blockIdx.x * 256 + threadIdx.x;           // 48*64 = 3072 elements
    if (i >= 48 * 64) return;
    int n = i >> 6, k = i & 63;
    float v = (n < D_OUT) ? W2[k * D_OUT + n] : 0.0f;
    unsigned short h = f32_to_bf16(v);
    W2Th[i] = h;
    W2Tl[i] = f32_to_bf16(v - bf16_f(h));
}

// ---------------------------------------------------------------------------
// Kernel 2 (MFMA): h = x @ W1 + b1. EXACT R4 core — FINAL. Five structures
// tried; 59.5 us is the floor (occupancy-proportional latency-bound, R10).
// Epilogue writes bf16 Y, bf16 src, fp8 Y8.
// ---------------------------------------------------------------------------
__global__ __launch_bounds__(64) void mlp1(const float* __restrict__ x,
                                           const unsigned short* __restrict__ W1T,
                                           const float* __restrict__ b1,
                                           const float* __restrict__ diag,
                                           unsigned short* __restrict__ Yb,
                                           unsigned char* __restrict__ Y08,
                                           unsigned short* __restrict__ srcb) {
    const int lane  = threadIdx.x;
    const int l15   = lane & 15;
    const int quad  = lane >> 4;
    const int mbase = blockIdx.x * 16;      // 6250 * 16 == 100000 exactly

    f32x4 acc[4] = {};
    const float* xrow = x + (size_t)(mbase + l15) * D_IN + quad * 8;

    #pragma unroll
    for (int ks = 0; ks < 8; ++ks) {
        float4 f0 = *(const float4*)(xrow + ks * 32);
        float4 f1 = *(const float4*)(xrow + ks * 32 + 4);
        union { short8 v; unsigned int u[4]; } a;
        a.u[0] = f32x2_to_bf16x2(f0.x, f0.y);
        a.u[1] = f32x2_to_bf16x2(f0.z, f0.w);
        a.u[2] = f32x2_to_bf16x2(f1.x, f1.y);
        a.u[3] = f32x2_to_bf16x2(f1.z, f1.w);

        #pragma unroll
        for (int ct = 0; ct < 4; ++ct) {
            short8 b = *(const short8*)(W1T + (ct * 16 + l15) * 256 + ks * 32 + quad * 8);
            acc[ct] = __builtin_amdgcn_mfma_f32_16x16x32_bf16(a.v, b, acc[ct], 0, 0, 0);
        }
    }

    float bias[4];
    #pragma unroll
    for (int ct = 0; ct < 4; ++ct) bias[ct] = b1[ct * 16 + l15];

    #pragma unroll
    for (int reg = 0; reg < 4; ++reg) {
        const int mr = mbase + quad * 4 + reg;
        const float dg = diag[mr];
        #pragma unroll
        for (int ct = 0; ct < 4; ++ct) {
            const int col = ct * 16 + l15;
            const float h = acc[ct][reg] + bias[ct];
            const size_t idx = (size_t)mr * 64 + col;
            Yb[idx]   = f32_to_bf16(h);
            srcb[idx] = f32_to_bf16(0.5f * dg * h);
            Y08[idx]  = f32_to_fp8(h);
        }
    }
}

// ---------------------------------------------------------------------------
// Kernel 3: one propagation step. EXACT R4 structure (known-best floor).
// Seven levers tried; only line-count reductions moved it; gathers at the
// 1-line/edge floor. Untouched this round.
// ---------------------------------------------------------------------------
__global__ __launch_bounds__(256) void prop_step(const unsigned short* __restrict__ Yb,
                                                 const unsigned char* __restrict__ Y8,
                                                 const unsigned short* __restrict__ srcb,
                                                 unsigned short* __restrict__ Ybo,
                                                 unsigned char* __restrict__ Yo8,
                                                 const int* __restrict__ rp,
                                                 const unsigned* __restrict__ ep4) {
    const int wid  = blockIdx.x * 4 + (threadIdx.x >> 6);   // 25000 waves
    const int lane = threadIdx.x & 63;
    const int g    = lane >> 4;         // row group 0..3
    const int fl   = lane & 15;         // feature-quad index
    const int row  = wid * 4 + g;       // exact: 100000 = 4 * 25000

    const int e0 = rp[row];
    const int e1 = rp[row + 1];

    const size_t fb = (size_t)row * 64 + fl * 4;
    const ushort4 ys4 = *(const ushort4*)(Yb + fb);
    const ushort4 sv4 = *(const ushort4*)(srcb + fb);
    const float4 yself = make_float4(bf16_f(ys4.x), bf16_f(ys4.y),
                                     bf16_f(ys4.z), bf16_f(ys4.w));
    const float4 sv    = make_float4(bf16_f(sv4.x), bf16_f(sv4.y),
                                     bf16_f(sv4.z), bf16_f(sv4.w));
    const unsigned char* Y8f = Y8 + fl * 4;

    float4 acc0 = make_float4(0.f, 0.f, 0.f, 0.f);
    float4 acc1 = acc0, acc2 = acc0, acc3 = acc0;

    int e = e0;
    // scalar head until e is 4-aligned (16B-aligned uint4 loads)
    int ea = (e0 + 3) & ~3;
    if (ea > e1) ea = e1;
    for (; e < ea; ++e) {
        unsigned p = ep4[e];
        unsigned b = *(const unsigned*)(Y8f + ((size_t)(p >> 15) << 6));
        fma4(acc0, edge_val(p), b);
    }
    for (; e + 8 <= e1; e += 8) {
        uint4 pa = *(const uint4*)(ep4 + e);
        uint4 pb = *(const uint4*)(ep4 + e + 4);
        unsigned b0 = *(const unsigned*)(Y8f + ((size_t)(pa.x >> 15) << 6));
        unsigned b1 = *(const unsigned*)(Y8f + ((size_t)(pa.y >> 15) << 6));
        unsigned b2 = *(const unsigned*)(Y8f + ((size_t)(pa.z >> 15) << 6));
        unsigned b3 = *(const unsigned*)(Y8f + ((size_t)(pa.w >> 15) << 6));
        unsigned b4 = *(const unsigned*)(Y8f + ((size_t)(pb.x >> 15) << 6));
        unsigned b5 = *(const unsigned*)(Y8f + ((size_t)(pb.y >> 15) << 6));
        unsigned b6 = *(const unsigned*)(Y8f + ((size_t)(pb.z >> 15) << 6));
        unsigned b7 = *(const unsigned*)(Y8f + ((size_t)(pb.w >> 15) << 6));
        fma4(acc0, edge_val(pa.x), b0);
        fma4(acc1, edge_val(pa.y), b1);
        fma4(acc2, edge_val(pa.z), b2);
        fma4(acc3, edge_val(pa.w), b3);
        fma4(acc0, edge_val(pb.x), b4);
        fma4(acc1, edge_val(pb.y), b5);
        fma4(acc2, edge_val(pb.z), b6);
        fma4(acc3, edge_val(pb.w), b7);
    }
    if (e + 4 <= e1) {
        uint4 pa = *(const uint4*)(ep4 + e);
        unsigned b0 = *(const unsigned*)(Y8f + ((size_t)(pa.x >> 15) << 6));
        unsigned b1 = *(const unsigned*)(Y8f + ((size_t)(pa.y >> 15) << 6));
        unsigned b2 = *(const unsigned*)(Y8f + ((size_t)(pa.z >> 15) << 6));
        unsigned b3 = *(const unsigned*)(Y8f + ((size_t)(pa.w >> 15) << 6));
        fma4(acc0, edge_val(pa.x), b0);
        fma4(acc1, edge_val(pa.y), b1);
        fma4(acc2, edge_val(pa.z), b2);
        fma4(acc3, edge_val(pa.w), b3);
        e += 4;
    }
    for (; e < e1; ++e) {
        unsigned p = ep4[e];
        unsigned b = *(const unsigned*)(Y8f + ((size_t)(p >> 15) << 6));
        fma4(acc0, edge_val(p), b);
    }

    float4 accs;
    accs.x = (acc0.x + acc1.x) + (acc2.x + acc3.x);
    accs.y = (acc0.y + acc1.y) + (acc2.y + acc3.y);
    accs.z = (acc0.z + acc1.z) + (acc2.z + acc3.z);
    accs.w = (acc0.w + acc1.w) + (acc2.w + acc3.w);

    float4 o;
    o.x = fmaf(0.5f, yself.x, fmaf(0.5f, accs.x, sv.x));
    o.y = fmaf(0.5f, yself.y, fmaf(0.5f, accs.y, sv.y));
    o.z = fmaf(0.5f, yself.z, fmaf(0.5f, accs.z, sv.z));
    o.w = fmaf(0.5f, yself.w, fmaf(0.5f, accs.w, sv.w));

    ushort4 ob;
    ob.x = f32_to_bf16(o.x); ob.y = f32_to_bf16(o.y);
    ob.z = f32_to_bf16(o.z); ob.w = f32_to_bf16(o.w);
    *(ushort4*)(Ybo + fb) = ob;
    int pk = __builtin_amdgcn_cvt_pk_fp8_f32(o.x, o.y, 0, false);   // bytes 0,1
    pk     = __builtin_amdgcn_cvt_pk_fp8_f32(o.z, o.w, pk, true);   // bytes 2,3
    *(unsigned*)(Yo8 + fb) = (unsigned)pk;
}

// ---------------------------------------------------------------------------
// Kernel 4 (MFMA): out = relu(Y) @ W2 + b2 — REWRITTEN mlp1-style.
// Old version: 1 node/thread, 391 blocks (1.5/CU, 14.5% occ), 128B-strided
// loads, 2560 serial FMAs/thread => 60.7 us latency-bound (hid below the
// top-5 cutoff for 11 rounds). New: 6250 one-wave blocks, 16 rows/wave,
// K=64 (2 MFMA K-steps), 3 col-tiles (48, 40 valid). A = relu(bf16 Y)
// exact (sign-bit clear); B = W2 hi+lo bf16 split (error ~2^-17 => no
// added output error). 12 MFMAs/wave; B operands 12KB L2-resident.
// ---------------------------------------------------------------------------
__global__ __launch_bounds__(64) void mlp2(const unsigned short* __restrict__ Yb,
                                           const unsigned short* __restrict__ W2Th,
                                           const unsigned short* __restrict__ W2Tl,
                                           const float* __restrict__ b2,
                                           float* __restrict__ out) {
    const int lane  = threadIdx.x;
    const int l15   = lane & 15;
    const int quad  = lane >> 4;
    const int mbase = blockIdx.x * 16;      // 6250 * 16 == 100000 exactly

    f32x4 acc[3] = {};
    const unsigned short* yrow = Yb + (size_t)(mbase + l15) * 64 + quad * 8;

    #pragma unroll
    for (int ks = 0; ks < 2; ++ks) {
        union { short8 v; unsigned short s[8]; } a;
        a.v = *(const short8*)(yrow + ks * 32);
        #pragma unroll
        for (int j = 0; j < 8; ++j)
            a.s[j] = (a.s[j] & 0x8000u) ? (unsigned short)0 : a.s[j];  // bf16 relu

        #pragma unroll
        for (int ct = 0; ct < 3; ++ct) {
            short8 bh = *(const short8*)(W2Th + (ct * 16 + l15) * 64 + ks * 32 + quad * 8);
            short8 bl = *(const short8*)(W2Tl + (ct * 16 + l15) * 64 + ks * 32 + quad * 8);
            acc[ct] = __builtin_amdgcn_mfma_f32_16x16x32_bf16(a.v, bh, acc[ct], 0, 0, 0);
            acc[ct] = __builtin_amdgcn_mfma_f32_16x16x32_bf16(a.v, bl, acc[ct], 0, 0, 0);
        }
    }

    float bias[3];
    #pragma unroll
    for (int ct = 0; ct < 3; ++ct) {
        const int col = ct * 16 + l15;
        bias[ct] = (col < D_OUT) ? b2[col] : 0.0f;
    }

    #pragma unroll
    for (int reg = 0; reg < 4; ++reg) {
        const int mr = mbase + quad * 4 + reg;
        #pragma unroll
        for (int ct = 0; ct < 3; ++ct) {
            const int col = ct * 16 + l15;
            if (col < D_OUT)
                out[(size_t)mr * D_OUT + col] = acc[ct][reg] + bias[ct];
        }
    }
}

// ---------------------------------------------------------------------------
extern "C" void kernel_launch(void* const* d_in, const int* in_sizes, int n_in,
                              void* d_out, int out_size, void* d_ws, size_t ws_size,
                              hipStream_t stream) {
    const float* x     = (const float*)d_in[0];
    const int*   erow  = (const int*)  d_in[1];
    const int*   ecol  = (const int*)  d_in[2];
    const float* evalv = (const float*)d_in[3];
    const float* diag  = (const float*)d_in[4];
    const float* W1    = (const float*)d_in[5];
    const float* b1    = (const float*)d_in[6];
    const float* W2    = (const float*)d_in[7];
    const float* b2    = (const float*)d_in[8];
    float* out = (float*)d_out;

    // workspace: Yb0|Yb1|srcb (bf16) | Y08|Y18 (fp8) | ep4 | rp | W1T | W2T hi/lo
    const size_t NV = (size_t)N_NODES * D_HID;
    unsigned short* Yb0  = (unsigned short*)d_ws;
    unsigned short* Yb1  = Yb0 + NV;
    unsigned short* srcb = Yb1 + NV;
    unsigned char*  Y08  = (unsigned char*)(srcb + NV);
    unsigned char*  Y18  = Y08 + NV;
    unsigned*       ep4  = (unsigned*)(Y18 + NV);
    int*            rp   = (int*)(ep4 + N_EDGES);
    unsigned short* W1T  = (unsigned short*)
        (((unsigned long long)(rp + N_NODES + 1) + 15ull) & ~15ull);
    unsigned short* W2Th = W1T + D_IN * D_HID;
    unsigned short* W2Tl = W2Th + 48 * 64;

    build_rowptr<<<(N_NODES + 1 + 255) / 256, 256, 0, stream>>>(erow, rp);
    pack_edges4<<<(N_EDGES + 255) / 256, 256, 0, stream>>>(ecol, evalv, ep4);
    prep_w1t<<<(D_IN * D_HID + 255) / 256, 256, 0, stream>>>(W1, W1T);
    prep_w2t<<<(48 * 64 + 255) / 256, 256, 0, stream>>>(W2, W2Th, W2Tl);
    mlp1<<<N_NODES / 16, 64, 0, stream>>>(x, W1T, b1, diag, Yb0, Y08, srcb);

    unsigned short* Yb[2] = {Yb0, Yb1};
    unsigned char*  Y8[2] = {Y08, Y18};
    for (int i = 0; i < PROP_N; ++i) {
        prop_step<<<N_NODES / 16, 256, 0, stream>>>(
            Yb[i & 1], Y8[i & 1], srcb, Yb[(i + 1) & 1], Y8[(i + 1) & 1], rp, ep4);
    }
    // PROP_N even -> final bf16 result in Yb0
    mlp2<<<N_NODES / 16, 64, 0, stream>>>(Yb0, W2Th, W2Tl, b2, out);
}